// Round 14
// baseline (104.592 us; speedup 1.0000x reference)
//
#include <hip/hip_runtime.h>

#define GN 512
#define HH 32
#define DD 64

typedef float v4f __attribute__((ext_vector_type(4)));
typedef unsigned int v4u __attribute__((ext_vector_type(4)));
typedef u_int32_t u32;
typedef u32 v2u __attribute__((ext_vector_type(2)));
typedef __bf16 v8bf __attribute__((ext_vector_type(8)));

__device__ __forceinline__ u32 f2bf(float f) {
  u32 u = __builtin_bit_cast(u32, f);
  return (u + 0x7fffu + ((u >> 16) & 1u)) >> 16;
}
__device__ __forceinline__ u32 pack2(float a, float b) {
  return f2bf(a) | (f2bf(b) << 16);
}

#define GLOAD16(g, l)                                                              \
  __builtin_amdgcn_global_load_lds((const __attribute__((address_space(1))) u32*)(g), \
                                   (__attribute__((address_space(3))) u32*)(l), 16, 0, 0)
#define VMCNT0 asm volatile("s_waitcnt vmcnt(0)" ::: "memory")

// ---------------- Stage 1: projections -> exp space -------------------------
__global__ __launch_bounds__(256) void kq_kernel(const float* __restrict__ rec,
                                                 const float* __restrict__ att,
                                                 const float* __restrict__ wq,
                                                 const float* __restrict__ wk,
                                                 const float* __restrict__ bias,
                                                 float* __restrict__ ekbuf,
                                                 float* __restrict__ eqbuf) {
  __shared__ float rr[512], ra[512];
  int tid = threadIdx.x;
  size_t base = (size_t)blockIdx.x * 8;
  const float* gr = rec + base * DD;
  const float* ga = att + base * DD;
  rr[tid] = gr[tid]; rr[tid + 256] = gr[tid + 256];
  ra[tid] = ga[tid]; ra[tid + 256] = ga[tid + 256];
  __syncthreads();
  int r = tid >> 5, h = tid & 31;
  float sk = bias[h], sq = 0.f;
  const float* rrow = &rr[r * DD];
  const float* arow = &ra[r * DD];
#pragma unroll 8
  for (int d = 0; d < DD; ++d) {
    sk += rrow[d] * wk[d * HH + h];
    sq += arow[d] * wq[d * HH + h];
  }
  const float C = 2.8853900817779268f;  // 2*log2(e)
  ekbuf[(base + r) * HH + h] = __builtin_exp2f(C * sk);
  eqbuf[(base + r) * HH + h] = __builtin_exp2f(C * sq);
}

// ------- Stage 2+3: heterogeneous blocks — escore OR transpose --------------
__global__ __launch_bounds__(256) void prep2_kernel(const float* __restrict__ adj,
                                                    const float* __restrict__ ek,
                                                    const float* __restrict__ eq,
                                                    const float* __restrict__ avec,
                                                    unsigned short* __restrict__ adjT,
                                                    unsigned short* __restrict__ adjBF,
                                                    unsigned short* __restrict__ Et) {
  __shared__ __align__(16) float smem[4608];  // escore: klt|ql ; transpose: t[64][65]
  int tid = threadIdx.x;
  int bid = blockIdx.x;
  int type = bid % 5, grp = bid / 5;

  if (type < 4) {
    // ================= escore block =================
    float (*klt)[68] = (float (*)[68])smem;        // [32 h][64 n + 4 pad]
    float (*ql)[36] = (float (*)[36])&smem[2176];  // [64 m][32 h + 4 pad]
    int e = grp * 4 + type;
    int b = e >> 6, rem = e & 63;
    int n0 = (rem & 7) * 64, m0 = (rem >> 3) * 64;

    const float* kb = ek + ((size_t)b * GN + n0) * HH;
    const float* qb = eq + ((size_t)b * GN + m0) * HH;
    int sr = tid >> 3, sp = tid & 7;
    v4f rk0 = *(const v4f*)(kb + sr * HH + sp * 4);
    v4f rq0 = *(const v4f*)(qb + sr * HH + sp * 4);
    v4f rk1 = *(const v4f*)(kb + (sr + 32) * HH + sp * 4);
    v4f rq1 = *(const v4f*)(qb + (sr + 32) * HH + sp * 4);
    *(v4f*)&ql[sr][sp * 4] = rq0;
    *(v4f*)&ql[sr + 32][sp * 4] = rq1;
#pragma unroll
    for (int ee = 0; ee < 4; ++ee) {
      klt[sp * 4 + ee][sr] = rk0[ee];
      klt[sp * 4 + ee][sr + 32] = rk1[ee];
    }

    float a2s[HH];
    float asum = 0.f;
#pragma unroll
    for (int h = 0; h < HH; ++h) {
      float av = avec[h];
      a2s[h] = 2.0f * av;
      asum += av;
    }
    __syncthreads();

    int mg = tid >> 4, ng = tid & 15;  // rows m0+mg+16i ; cols n0+4ng..+3
    v4f acc[4];
#pragma unroll
    for (int i = 0; i < 4; ++i) acc[i] = (v4f){0.f, 0.f, 0.f, 0.f};

#pragma unroll
    for (int h4 = 0; h4 < 8; ++h4) {
      v4f kv[4], qv[4];
#pragma unroll
      for (int ee = 0; ee < 4; ++ee) kv[ee] = *(const v4f*)&klt[h4 * 4 + ee][4 * ng];
#pragma unroll
      for (int i = 0; i < 4; ++i) qv[i] = *(const v4f*)&ql[mg + 16 * i][h4 * 4];
      float a0 = a2s[h4 * 4 + 0], a1 = a2s[h4 * 4 + 1];
      float a2 = a2s[h4 * 4 + 2], a3 = a2s[h4 * 4 + 3];
#pragma unroll
      for (int i = 0; i < 4; ++i) {
        v4f f0 = kv[0] * qv[i][0] + 1.0f;
        v4f f1 = kv[1] * qv[i][1] + 1.0f;
        v4f f2 = kv[2] * qv[i][2] + 1.0f;
        v4f f3 = kv[3] * qv[i][3] + 1.0f;
        v4f den0 = f0 * f1, den1 = f2 * f3;
        v4f num0 = a0 * f1 + a1 * f0;
        v4f num1 = a2 * f3 + a3 * f2;
        v4f r0, r1;
#pragma unroll
        for (int ee = 0; ee < 4; ++ee) {
          r0[ee] = __builtin_amdgcn_rcpf(den0[ee]);
          r1[ee] = __builtin_amdgcn_rcpf(den1[ee]);
        }
        acc[i] += num0 * r0;
        acc[i] += num1 * r1;
      }
    }
#pragma unroll
    for (int i = 0; i < 4; ++i) {
      v4f s = asum - acc[i];
      v2u p = {pack2(s[0], s[1]), pack2(s[2], s[3])};
      *(v2u*)(Et + ((size_t)b * GN + m0 + mg + 16 * i) * GN + n0 + 4 * ng) = p;
    }
  } else {
    // ================= transpose block (4 tiles) =================
    float (*t)[65] = (float (*)[65])smem;
#pragma unroll 1
    for (int l = 0; l < 4; ++l) {
      int tt = grp * 4 + l;
      int b = tt >> 6, rem = tt & 63;
      int c0 = (rem & 7) * 64, r0 = (rem >> 3) * 64;
      const float* ab = adj + (size_t)b * GN * GN;
      unsigned short* ob = adjT + (size_t)b * GN * GN;
      unsigned short* of = adjBF + (size_t)b * GN * GN;
#pragma unroll
      for (int k = 0; k < 4; ++k) {
        int v = tid + k * 256;
        int row = v >> 4, seg = v & 15;
        v4f f = *(const v4f*)(ab + (size_t)(r0 + row) * GN + c0 + seg * 4);
        t[row][seg * 4 + 0] = f[0];
        t[row][seg * 4 + 1] = f[1];
        t[row][seg * 4 + 2] = f[2];
        t[row][seg * 4 + 3] = f[3];
        v2u p = {pack2(f[0], f[1]), pack2(f[2], f[3])};
        *(v2u*)(of + (size_t)(r0 + row) * GN + c0 + seg * 4) = p;
      }
      __syncthreads();
      {
        int c = tid >> 2;
        int rs = (tid & 3) * 16;
        v4u p0, p1;
#pragma unroll
        for (int j = 0; j < 4; ++j) {
          p0[j] = pack2(t[rs + 2 * j][c], t[rs + 2 * j + 1][c]);
          p1[j] = pack2(t[rs + 8 + 2 * j][c], t[rs + 9 + 2 * j][c]);
        }
        unsigned short* dst = ob + (size_t)(c0 + c) * GN + r0 + rs;
        *(v4u*)dst = p0;
        *(v4u*)(dst + 8) = p1;
      }
      __syncthreads();
    }
  }
}

// ---------------- Stage 4/5: batched bf16 GEMM (round-12 passing version) ---
#define SWZ(r, s) ((s) ^ ((r) & 7))

template <bool OUTF32>
__global__ __launch_bounds__(256) void gemm_bt(const unsigned short* __restrict__ A,
                                               const unsigned short* __restrict__ Bt,
                                               void* __restrict__ Cv) {
  __shared__ unsigned short At[2][128 * 64];  // 2 x 16 KiB
  __shared__ unsigned short Bs[2][128 * 64];
  int bid = blockIdx.x;
  int swz = (bid & 7) * 64 + (bid >> 3);  // XCD-chunked, bijective
  int b = swz >> 4;
  int row0 = ((swz >> 2) & 3) * 128;
  int col0 = (swz & 3) * 128;
  int tid = threadIdx.x, lane = tid & 63, wave = tid >> 6;
  int wr = wave >> 1, wc = wave & 1;
  const unsigned short* Ab = A + (size_t)b * GN * GN;
  const unsigned short* Bb = Bt + (size_t)b * GN * GN;

  v4f acc[4][4];
#pragma unroll
  for (int i = 0; i < 4; ++i)
#pragma unroll
    for (int j = 0; j < 4; ++j) acc[i][j] = (v4f){0.f, 0.f, 0.f, 0.f};

  int cc_r[4], cc_s[4];
#pragma unroll
  for (int i = 0; i < 4; ++i) {
    int c = i * 256 + tid;
    cc_r[i] = c >> 3;
    cc_s[i] = SWZ(c >> 3, c & 7);
  }

#define STAGE(buf, kt)                                                                   \
  {                                                                                      \
    _Pragma("unroll") for (int i = 0; i < 4; ++i) {                                      \
      const unsigned short* ga = Ab + (size_t)(row0 + cc_r[i]) * GN + (kt)*64 + cc_s[i] * 8; \
      const unsigned short* gb = Bb + (size_t)(col0 + cc_r[i]) * GN + (kt)*64 + cc_s[i] * 8; \
      GLOAD16(ga, (char*)&At[buf][0] + (i * 256 + wave * 64) * 16);                      \
      GLOAD16(gb, (char*)&Bs[buf][0] + (i * 256 + wave * 64) * 16);                      \
    }                                                                                    \
  }

#define COMPUTE(buf)                                                                     \
  {                                                                                      \
    int lr = lane & 15, s16 = lane >> 4;                                                 \
    _Pragma("unroll") for (int h = 0; h < 2; ++h) {                                      \
      int sl = h * 4 + s16;                                                              \
      v8bf af[4], bfv[4];                                                                \
      _Pragma("unroll") for (int i = 0; i < 4; ++i) {                                    \
        int r = wr * 64 + i * 16 + lr;                                                   \
        af[i] = *(const v8bf*)&At[buf][r * 64 + SWZ(r, sl) * 8];                         \
      }                                                                                  \
      _Pragma("unroll") for (int j = 0; j < 4; ++j) {                                    \
        int r = wc * 64 + j * 16 + lr;                                                   \
        bfv[j] = *(const v8bf*)&Bs[buf][r * 64 + SWZ(r, sl) * 8];                        \
      }                                                                                  \
      _Pragma("unroll") for (int i = 0; i < 4; ++i)                                      \
          _Pragma("unroll") for (int j = 0; j < 4; ++j) acc[i][j] =                      \
          __builtin_amdgcn_mfma_f32_16x16x32_bf16(af[i], bfv[j], acc[i][j], 0, 0, 0);    \
    }                                                                                    \
  }

  STAGE(0, 0);
  VMCNT0;
  __builtin_amdgcn_s_barrier();
#pragma unroll
  for (int kt = 0; kt < 7; ++kt) {
    int cur = kt & 1;
    STAGE(cur ^ 1, kt + 1);
    COMPUTE(cur);
    VMCNT0;
    __builtin_amdgcn_s_barrier();
  }
  COMPUTE(1);

  int lc = lane & 15;
  int lrow4 = (lane >> 4) * 4;
#pragma unroll
  for (int i = 0; i < 4; ++i) {
#pragma unroll
    for (int j = 0; j < 4; ++j) {
      int gr = row0 + wr * 64 + i * 16 + lrow4;
      int gc = col0 + wc * 64 + j * 16 + lc;
#pragma unroll
      for (int e = 0; e < 4; ++e) {
        float v = acc[i][j][e];
        if constexpr (OUTF32)
          ((float*)Cv)[(size_t)b * GN * GN + (size_t)(gr + e) * GN + gc] = v;
        else
          ((unsigned short*)Cv)[(size_t)b * GN * GN + (size_t)(gr + e) * GN + gc] =
              (unsigned short)f2bf(v);
      }
    }
  }
#undef STAGE
#undef COMPUTE
}

// ---------------- launch ----------------------------------------------------
// MEASUREMENT ROUND: each GEMM launched TWICE (idempotent — identical bytes
// rewritten). dur_us_14 - dur_us_12 = gemm1 + gemm2 wall time, exactly.
extern "C" void kernel_launch(void* const* d_in, const int* in_sizes, int n_in,
                              void* d_out, int out_size, void* d_ws, size_t ws_size,
                              hipStream_t stream) {
  const float* receiver  = (const float*)d_in[0];
  const float* attendant = (const float*)d_in[1];
  const float* adj       = (const float*)d_in[2];
  const float* wq        = (const float*)d_in[3];
  const float* wk        = (const float*)d_in[4];
  const float* bias      = (const float*)d_in[5];
  const float* avec      = (const float*)d_in[6];
  float* out = (float*)d_out;

  char* ws = (char*)d_ws;
  float* ekbuf          = (float*)(ws);                          // 2 MiB
  float* eqbuf          = (float*)(ws + (2u << 20));             // 2 MiB
  unsigned short* Et    = (unsigned short*)(ws + (4u << 20));    // 16 MiB
  unsigned short* adjT  = (unsigned short*)(ws + (20u << 20));   // 16 MiB
  unsigned short* adjBF = (unsigned short*)(ws + (36u << 20));   // 16 MiB
  unsigned short* Tbuf  = (unsigned short*)(ws + (52u << 20));   // 16 MiB

  kq_kernel<<<dim3(2048), dim3(256), 0, stream>>>(receiver, attendant, wq, wk, bias,
                                                  ekbuf, eqbuf);
  prep2_kernel<<<dim3(2560), dim3(256), 0, stream>>>(adj, ekbuf, eqbuf, avec,
                                                     adjT, adjBF, Et);
  // T = adjBF @ Et^T  -> bf16   (launched twice: timing probe)
  gemm_bt<false><<<dim3(512), dim3(256), 0, stream>>>(adjBF, Et, Tbuf);
  gemm_bt<false><<<dim3(512), dim3(256), 0, stream>>>(adjBF, Et, Tbuf);
  // out = Tbuf @ adjT^T -> f32  (launched twice: timing probe)
  gemm_bt<true><<<dim3(512), dim3(256), 0, stream>>>(Tbuf, adjT, out);
  gemm_bt<true><<<dim3(512), dim3(256), 0, stream>>>(Tbuf, adjT, out);
}

// Round 15
// 88.466 us; speedup vs baseline: 1.1823x; 1.1823x over previous
//
#include <hip/hip_runtime.h>

#define GN 512
#define HH 32
#define DD 64

typedef float v4f __attribute__((ext_vector_type(4)));
typedef unsigned int v4u __attribute__((ext_vector_type(4)));
typedef u_int32_t u32;
typedef u32 v2u __attribute__((ext_vector_type(2)));
typedef __bf16 v8bf __attribute__((ext_vector_type(8)));

__device__ __forceinline__ u32 f2bf(float f) {
  u32 u = __builtin_bit_cast(u32, f);
  return (u + 0x7fffu + ((u >> 16) & 1u)) >> 16;
}
__device__ __forceinline__ u32 pack2(float a, float b) {
  return f2bf(a) | (f2bf(b) << 16);
}

#define GLOAD16(g, l)                                                              \
  __builtin_amdgcn_global_load_lds((const __attribute__((address_space(1))) u32*)(g), \
                                   (__attribute__((address_space(3))) u32*)(l), 16, 0, 0)
#define VMCNT0 asm volatile("s_waitcnt vmcnt(0)" ::: "memory")

// ---------------- Stage 1: projections -> exp space -------------------------
__global__ __launch_bounds__(256) void kq_kernel(const float* __restrict__ rec,
                                                 const float* __restrict__ att,
                                                 const float* __restrict__ wq,
                                                 const float* __restrict__ wk,
                                                 const float* __restrict__ bias,
                                                 float* __restrict__ ekbuf,
                                                 float* __restrict__ eqbuf) {
  __shared__ float rr[512], ra[512];
  int tid = threadIdx.x;
  size_t base = (size_t)blockIdx.x * 8;
  const float* gr = rec + base * DD;
  const float* ga = att + base * DD;
  rr[tid] = gr[tid]; rr[tid + 256] = gr[tid + 256];
  ra[tid] = ga[tid]; ra[tid + 256] = ga[tid + 256];
  __syncthreads();
  int r = tid >> 5, h = tid & 31;
  float sk = bias[h], sq = 0.f;
  const float* rrow = &rr[r * DD];
  const float* arow = &ra[r * DD];
#pragma unroll 8
  for (int d = 0; d < DD; ++d) {
    sk += rrow[d] * wk[d * HH + h];
    sq += arow[d] * wq[d * HH + h];
  }
  const float C = 2.8853900817779268f;  // 2*log2(e)
  ekbuf[(base + r) * HH + h] = __builtin_exp2f(C * sk);
  eqbuf[(base + r) * HH + h] = __builtin_exp2f(C * sq);
}

// ------- Stage 2+3: heterogeneous 1:1 interleave — escore | transpose -------
// Even bid -> escore tile; odd bid -> ONE transpose tile (was 4 serial tiles:
// exposed ~600cyc latency chains + clumped HBM; 1-tile blocks spread traffic
// uniformly under escore's VALU time).
__global__ __launch_bounds__(256) void prep2_kernel(const float* __restrict__ adj,
                                                    const float* __restrict__ ek,
                                                    const float* __restrict__ eq,
                                                    const float* __restrict__ avec,
                                                    unsigned short* __restrict__ adjT,
                                                    unsigned short* __restrict__ adjBF,
                                                    unsigned short* __restrict__ Et) {
  __shared__ __align__(16) float smem[4608];  // escore: klt|ql ; transpose: t[64][65]
  int tid = threadIdx.x;
  int bid = blockIdx.x;
  int type = bid & 1, grp = bid >> 1;

  if (type == 0) {
    // ================= escore block =================
    float (*klt)[68] = (float (*)[68])smem;        // [32 h][64 n + 4 pad]
    float (*ql)[36] = (float (*)[36])&smem[2176];  // [64 m][32 h + 4 pad]
    int e = grp;
    int b = e >> 6, rem = e & 63;
    int n0 = (rem & 7) * 64, m0 = (rem >> 3) * 64;

    const float* kb = ek + ((size_t)b * GN + n0) * HH;
    const float* qb = eq + ((size_t)b * GN + m0) * HH;
    int sr = tid >> 3, sp = tid & 7;
    v4f rk0 = *(const v4f*)(kb + sr * HH + sp * 4);
    v4f rq0 = *(const v4f*)(qb + sr * HH + sp * 4);
    v4f rk1 = *(const v4f*)(kb + (sr + 32) * HH + sp * 4);
    v4f rq1 = *(const v4f*)(qb + (sr + 32) * HH + sp * 4);
    *(v4f*)&ql[sr][sp * 4] = rq0;
    *(v4f*)&ql[sr + 32][sp * 4] = rq1;
#pragma unroll
    for (int ee = 0; ee < 4; ++ee) {
      klt[sp * 4 + ee][sr] = rk0[ee];
      klt[sp * 4 + ee][sr + 32] = rk1[ee];
    }

    float a2s[HH];
    float asum = 0.f;
#pragma unroll
    for (int h = 0; h < HH; ++h) {
      float av = avec[h];
      a2s[h] = 2.0f * av;
      asum += av;
    }
    __syncthreads();

    int mg = tid >> 4, ng = tid & 15;  // rows m0+mg+16i ; cols n0+4ng..+3
    v4f acc[4];
#pragma unroll
    for (int i = 0; i < 4; ++i) acc[i] = (v4f){0.f, 0.f, 0.f, 0.f};

#pragma unroll
    for (int h4 = 0; h4 < 8; ++h4) {
      v4f kv[4], qv[4];
#pragma unroll
      for (int ee = 0; ee < 4; ++ee) kv[ee] = *(const v4f*)&klt[h4 * 4 + ee][4 * ng];
#pragma unroll
      for (int i = 0; i < 4; ++i) qv[i] = *(const v4f*)&ql[mg + 16 * i][h4 * 4];
      float a0 = a2s[h4 * 4 + 0], a1 = a2s[h4 * 4 + 1];
      float a2 = a2s[h4 * 4 + 2], a3 = a2s[h4 * 4 + 3];
#pragma unroll
      for (int i = 0; i < 4; ++i) {
        v4f f0 = kv[0] * qv[i][0] + 1.0f;
        v4f f1 = kv[1] * qv[i][1] + 1.0f;
        v4f f2 = kv[2] * qv[i][2] + 1.0f;
        v4f f3 = kv[3] * qv[i][3] + 1.0f;
        v4f den0 = f0 * f1, den1 = f2 * f3;
        v4f num0 = a0 * f1 + a1 * f0;
        v4f num1 = a2 * f3 + a3 * f2;
        v4f r0, r1;
#pragma unroll
        for (int ee = 0; ee < 4; ++ee) {
          r0[ee] = __builtin_amdgcn_rcpf(den0[ee]);
          r1[ee] = __builtin_amdgcn_rcpf(den1[ee]);
        }
        acc[i] += num0 * r0;
        acc[i] += num1 * r1;
      }
    }
#pragma unroll
    for (int i = 0; i < 4; ++i) {
      v4f s = asum - acc[i];
      v2u p = {pack2(s[0], s[1]), pack2(s[2], s[3])};
      *(v2u*)(Et + ((size_t)b * GN + m0 + mg + 16 * i) * GN + n0 + 4 * ng) = p;
    }
  } else {
    // ================= transpose block (ONE tile) =================
    float (*t)[65] = (float (*)[65])smem;
    int tt = grp;
    int b = tt >> 6, rem = tt & 63;
    int c0 = (rem & 7) * 64, r0 = (rem >> 3) * 64;
    const float* ab = adj + (size_t)b * GN * GN;
    unsigned short* ob = adjT + (size_t)b * GN * GN;
    unsigned short* of = adjBF + (size_t)b * GN * GN;
#pragma unroll
    for (int k = 0; k < 4; ++k) {
      int v = tid + k * 256;
      int row = v >> 4, seg = v & 15;
      v4f f = *(const v4f*)(ab + (size_t)(r0 + row) * GN + c0 + seg * 4);
      t[row][seg * 4 + 0] = f[0];
      t[row][seg * 4 + 1] = f[1];
      t[row][seg * 4 + 2] = f[2];
      t[row][seg * 4 + 3] = f[3];
      v2u p = {pack2(f[0], f[1]), pack2(f[2], f[3])};
      *(v2u*)(of + (size_t)(r0 + row) * GN + c0 + seg * 4) = p;
    }
    __syncthreads();
    {
      int c = tid >> 2;
      int rs = (tid & 3) * 16;
      v4u p0, p1;
#pragma unroll
      for (int j = 0; j < 4; ++j) {
        p0[j] = pack2(t[rs + 2 * j][c], t[rs + 2 * j + 1][c]);
        p1[j] = pack2(t[rs + 8 + 2 * j][c], t[rs + 9 + 2 * j][c]);
      }
      unsigned short* dst = ob + (size_t)(c0 + c) * GN + r0 + rs;
      *(v4u*)dst = p0;
      *(v4u*)(dst + 8) = p1;
    }
  }
}

// ---------------- Stage 4/5: batched bf16 GEMM (round-12 passing version) ---
#define SWZ(r, s) ((s) ^ ((r) & 7))

template <bool OUTF32>
__global__ __launch_bounds__(256) void gemm_bt(const unsigned short* __restrict__ A,
                                               const unsigned short* __restrict__ Bt,
                                               void* __restrict__ Cv) {
  __shared__ unsigned short At[2][128 * 64];  // 2 x 16 KiB
  __shared__ unsigned short Bs[2][128 * 64];
  int bid = blockIdx.x;
  int swz = (bid & 7) * 64 + (bid >> 3);  // XCD-chunked, bijective
  int b = swz >> 4;
  int row0 = ((swz >> 2) & 3) * 128;
  int col0 = (swz & 3) * 128;
  int tid = threadIdx.x, lane = tid & 63, wave = tid >> 6;
  int wr = wave >> 1, wc = wave & 1;
  const unsigned short* Ab = A + (size_t)b * GN * GN;
  const unsigned short* Bb = Bt + (size_t)b * GN * GN;

  v4f acc[4][4];
#pragma unroll
  for (int i = 0; i < 4; ++i)
#pragma unroll
    for (int j = 0; j < 4; ++j) acc[i][j] = (v4f){0.f, 0.f, 0.f, 0.f};

  int cc_r[4], cc_s[4];
#pragma unroll
  for (int i = 0; i < 4; ++i) {
    int c = i * 256 + tid;
    cc_r[i] = c >> 3;
    cc_s[i] = SWZ(c >> 3, c & 7);
  }

#define STAGE(buf, kt)                                                                   \
  {                                                                                      \
    _Pragma("unroll") for (int i = 0; i < 4; ++i) {                                      \
      const unsigned short* ga = Ab + (size_t)(row0 + cc_r[i]) * GN + (kt)*64 + cc_s[i] * 8; \
      const unsigned short* gb = Bb + (size_t)(col0 + cc_r[i]) * GN + (kt)*64 + cc_s[i] * 8; \
      GLOAD16(ga, (char*)&At[buf][0] + (i * 256 + wave * 64) * 16);                      \
      GLOAD16(gb, (char*)&Bs[buf][0] + (i * 256 + wave * 64) * 16);                      \
    }                                                                                    \
  }

#define COMPUTE(buf)                                                                     \
  {                                                                                      \
    int lr = lane & 15, s16 = lane >> 4;                                                 \
    _Pragma("unroll") for (int h = 0; h < 2; ++h) {                                      \
      int sl = h * 4 + s16;                                                              \
      v8bf af[4], bfv[4];                                                                \
      _Pragma("unroll") for (int i = 0; i < 4; ++i) {                                    \
        int r = wr * 64 + i * 16 + lr;                                                   \
        af[i] = *(const v8bf*)&At[buf][r * 64 + SWZ(r, sl) * 8];                         \
      }                                                                                  \
      _Pragma("unroll") for (int j = 0; j < 4; ++j) {                                    \
        int r = wc * 64 + j * 16 + lr;                                                   \
        bfv[j] = *(const v8bf*)&Bs[buf][r * 64 + SWZ(r, sl) * 8];                        \
      }                                                                                  \
      _Pragma("unroll") for (int i = 0; i < 4; ++i)                                      \
          _Pragma("unroll") for (int j = 0; j < 4; ++j) acc[i][j] =                      \
          __builtin_amdgcn_mfma_f32_16x16x32_bf16(af[i], bfv[j], acc[i][j], 0, 0, 0);    \
    }                                                                                    \
  }

  STAGE(0, 0);
  VMCNT0;
  __builtin_amdgcn_s_barrier();
#pragma unroll
  for (int kt = 0; kt < 7; ++kt) {
    int cur = kt & 1;
    STAGE(cur ^ 1, kt + 1);
    COMPUTE(cur);
    VMCNT0;
    __builtin_amdgcn_s_barrier();
  }
  COMPUTE(1);

  int lc = lane & 15;
  int lrow4 = (lane >> 4) * 4;
#pragma unroll
  for (int i = 0; i < 4; ++i) {
#pragma unroll
    for (int j = 0; j < 4; ++j) {
      int gr = row0 + wr * 64 + i * 16 + lrow4;
      int gc = col0 + wc * 64 + j * 16 + lc;
#pragma unroll
      for (int e = 0; e < 4; ++e) {
        float v = acc[i][j][e];
        if constexpr (OUTF32)
          ((float*)Cv)[(size_t)b * GN * GN + (size_t)(gr + e) * GN + gc] = v;
        else
          ((unsigned short*)Cv)[(size_t)b * GN * GN + (size_t)(gr + e) * GN + gc] =
              (unsigned short)f2bf(v);
      }
    }
  }
#undef STAGE
#undef COMPUTE
}

// ---------------- launch ----------------------------------------------------
extern "C" void kernel_launch(void* const* d_in, const int* in_sizes, int n_in,
                              void* d_out, int out_size, void* d_ws, size_t ws_size,
                              hipStream_t stream) {
  const float* receiver  = (const float*)d_in[0];
  const float* attendant = (const float*)d_in[1];
  const float* adj       = (const float*)d_in[2];
  const float* wq        = (const float*)d_in[3];
  const float* wk        = (const float*)d_in[4];
  const float* bias      = (const float*)d_in[5];
  const float* avec      = (const float*)d_in[6];
  float* out = (float*)d_out;

  char* ws = (char*)d_ws;
  float* ekbuf          = (float*)(ws);                          // 2 MiB
  float* eqbuf          = (float*)(ws + (2u << 20));             // 2 MiB
  unsigned short* Et    = (unsigned short*)(ws + (4u << 20));    // 16 MiB
  unsigned short* adjT  = (unsigned short*)(ws + (20u << 20));   // 16 MiB
  unsigned short* adjBF = (unsigned short*)(ws + (36u << 20));   // 16 MiB
  unsigned short* Tbuf  = (unsigned short*)(ws + (52u << 20));   // 16 MiB

  kq_kernel<<<dim3(2048), dim3(256), 0, stream>>>(receiver, attendant, wq, wk, bias,
                                                  ekbuf, eqbuf);
  prep2_kernel<<<dim3(4096), dim3(256), 0, stream>>>(adj, ekbuf, eqbuf, avec,
                                                     adjT, adjBF, Et);
  // T = adjBF @ Et^T  -> bf16
  gemm_bt<false><<<dim3(512), dim3(256), 0, stream>>>(adjBF, Et, Tbuf);
  // out = Tbuf @ adjT^T -> f32
  gemm_bt<true><<<dim3(512), dim3(256), 0, stream>>>(Tbuf, adjT, out);
}

// Round 16
// 73.752 us; speedup vs baseline: 1.4182x; 1.1995x over previous
//
#include <hip/hip_runtime.h>

#define GN 512
#define HH 32
#define DD 64

typedef float v4f __attribute__((ext_vector_type(4)));
typedef unsigned int v4u __attribute__((ext_vector_type(4)));
typedef u_int32_t u32;
typedef u32 v2u __attribute__((ext_vector_type(2)));
typedef __bf16 v8bf __attribute__((ext_vector_type(8)));

__device__ __forceinline__ u32 f2bf(float f) {
  u32 u = __builtin_bit_cast(u32, f);
  return (u + 0x7fffu + ((u >> 16) & 1u)) >> 16;
}
__device__ __forceinline__ u32 pack2(float a, float b) {
  return f2bf(a) | (f2bf(b) << 16);
}

#define GLOAD16(g, l)                                                              \
  __builtin_amdgcn_global_load_lds((const __attribute__((address_space(1))) u32*)(g), \
                                   (__attribute__((address_space(3))) u32*)(l), 16, 0, 0)
#define VMCNT0 asm volatile("s_waitcnt vmcnt(0)" ::: "memory")

// ---------------- Stage 1: projections -> exp space -------------------------
__global__ __launch_bounds__(256) void kq_kernel(const float* __restrict__ rec,
                                                 const float* __restrict__ att,
                                                 const float* __restrict__ wq,
                                                 const float* __restrict__ wk,
                                                 const float* __restrict__ bias,
                                                 float* __restrict__ ekbuf,
                                                 float* __restrict__ eqbuf) {
  __shared__ float rr[512], ra[512];
  int tid = threadIdx.x;
  size_t base = (size_t)blockIdx.x * 8;
  const float* gr = rec + base * DD;
  const float* ga = att + base * DD;
  rr[tid] = gr[tid]; rr[tid + 256] = gr[tid + 256];
  ra[tid] = ga[tid]; ra[tid + 256] = ga[tid + 256];
  __syncthreads();
  int r = tid >> 5, h = tid & 31;
  float sk = bias[h], sq = 0.f;
  const float* rrow = &rr[r * DD];
  const float* arow = &ra[r * DD];
#pragma unroll 8
  for (int d = 0; d < DD; ++d) {
    sk += rrow[d] * wk[d * HH + h];
    sq += arow[d] * wq[d * HH + h];
  }
  const float C = 2.8853900817779268f;  // 2*log2(e)
  ekbuf[(base + r) * HH + h] = __builtin_exp2f(C * sk);
  eqbuf[(base + r) * HH + h] = __builtin_exp2f(C * sq);
}

// ------- Stage 2+3: heterogeneous blocks — escore OR transpose (r12 4:1) ----
__global__ __launch_bounds__(256) void prep2_kernel(const float* __restrict__ adj,
                                                    const float* __restrict__ ek,
                                                    const float* __restrict__ eq,
                                                    const float* __restrict__ avec,
                                                    unsigned short* __restrict__ adjT,
                                                    unsigned short* __restrict__ adjBF,
                                                    unsigned short* __restrict__ Et) {
  __shared__ __align__(16) float smem[4608];  // escore: klt|ql ; transpose: t[64][65]
  int tid = threadIdx.x;
  int bid = blockIdx.x;
  int type = bid % 5, grp = bid / 5;

  if (type < 4) {
    // ================= escore block =================
    float (*klt)[68] = (float (*)[68])smem;        // [32 h][64 n + 4 pad]
    float (*ql)[36] = (float (*)[36])&smem[2176];  // [64 m][32 h + 4 pad]
    int e = grp * 4 + type;
    int b = e >> 6, rem = e & 63;
    int n0 = (rem & 7) * 64, m0 = (rem >> 3) * 64;

    const float* kb = ek + ((size_t)b * GN + n0) * HH;
    const float* qb = eq + ((size_t)b * GN + m0) * HH;
    int sr = tid >> 3, sp = tid & 7;
    v4f rk0 = *(const v4f*)(kb + sr * HH + sp * 4);
    v4f rq0 = *(const v4f*)(qb + sr * HH + sp * 4);
    v4f rk1 = *(const v4f*)(kb + (sr + 32) * HH + sp * 4);
    v4f rq1 = *(const v4f*)(qb + (sr + 32) * HH + sp * 4);
    *(v4f*)&ql[sr][sp * 4] = rq0;
    *(v4f*)&ql[sr + 32][sp * 4] = rq1;
#pragma unroll
    for (int ee = 0; ee < 4; ++ee) {
      klt[sp * 4 + ee][sr] = rk0[ee];
      klt[sp * 4 + ee][sr + 32] = rk1[ee];
    }

    float a2s[HH];
    float asum = 0.f;
#pragma unroll
    for (int h = 0; h < HH; ++h) {
      float av = avec[h];
      a2s[h] = 2.0f * av;
      asum += av;
    }
    __syncthreads();

    int mg = tid >> 4, ng = tid & 15;  // rows m0+mg+16i ; cols n0+4ng..+3
    v4f acc[4];
#pragma unroll
    for (int i = 0; i < 4; ++i) acc[i] = (v4f){0.f, 0.f, 0.f, 0.f};

#pragma unroll
    for (int h4 = 0; h4 < 8; ++h4) {
      v4f kv[4], qv[4];
#pragma unroll
      for (int ee = 0; ee < 4; ++ee) kv[ee] = *(const v4f*)&klt[h4 * 4 + ee][4 * ng];
#pragma unroll
      for (int i = 0; i < 4; ++i) qv[i] = *(const v4f*)&ql[mg + 16 * i][h4 * 4];
      float a0 = a2s[h4 * 4 + 0], a1 = a2s[h4 * 4 + 1];
      float a2 = a2s[h4 * 4 + 2], a3 = a2s[h4 * 4 + 3];
#pragma unroll
      for (int i = 0; i < 4; ++i) {
        v4f f0 = kv[0] * qv[i][0] + 1.0f;
        v4f f1 = kv[1] * qv[i][1] + 1.0f;
        v4f f2 = kv[2] * qv[i][2] + 1.0f;
        v4f f3 = kv[3] * qv[i][3] + 1.0f;
        // 4-term rcp fusion: sum 2a_e/f_e = num/den, one rcp per 4 h-values
        v4f f01 = f0 * f1, f23 = f2 * f3;
        v4f den = f01 * f23;
        v4f t01 = a0 * f1 + a1 * f0;
        v4f t23 = a2 * f3 + a3 * f2;
        v4f num = t01 * f23 + t23 * f01;
        v4f r;
#pragma unroll
        for (int ee = 0; ee < 4; ++ee) r[ee] = __builtin_amdgcn_rcpf(den[ee]);
        acc[i] += num * r;
      }
    }
#pragma unroll
    for (int i = 0; i < 4; ++i) {
      v4f s = asum - acc[i];
      v2u p = {pack2(s[0], s[1]), pack2(s[2], s[3])};
      *(v2u*)(Et + ((size_t)b * GN + m0 + mg + 16 * i) * GN + n0 + 4 * ng) = p;
    }
  } else {
    // ========== transpose block: 4 tiles, depth-2 register pipeline ==========
    // Next tile's HBM loads issue before current tile's LDS/store phase:
    // 3 of 4 round-trips hidden.
    float (*t)[65] = (float (*)[65])smem;
    int base_tt = grp * 4;
    v4f ra[4], rb[4];

#define TLOAD(dst, l)                                                          \
    {                                                                          \
      int tt = base_tt + (l);                                                  \
      int b_ = tt >> 6, rem_ = tt & 63;                                        \
      int c0_ = (rem_ & 7) * 64, r0_ = (rem_ >> 3) * 64;                       \
      const float* ab_ = adj + (size_t)b_ * GN * GN;                           \
      _Pragma("unroll") for (int k = 0; k < 4; ++k) {                          \
        int v = tid + k * 256;                                                 \
        int row = v >> 4, seg = v & 15;                                        \
        dst[k] = *(const v4f*)(ab_ + (size_t)(r0_ + row) * GN + c0_ + seg * 4); \
      }                                                                        \
    }

#define TPROCESS(src, l)                                                       \
    {                                                                          \
      int tt = base_tt + (l);                                                  \
      int b_ = tt >> 6, rem_ = tt & 63;                                        \
      int c0_ = (rem_ & 7) * 64, r0_ = (rem_ >> 3) * 64;                       \
      unsigned short* ob_ = adjT + (size_t)b_ * GN * GN;                       \
      unsigned short* of_ = adjBF + (size_t)b_ * GN * GN;                      \
      _Pragma("unroll") for (int k = 0; k < 4; ++k) {                          \
        int v = tid + k * 256;                                                 \
        int row = v >> 4, seg = v & 15;                                        \
        v4f f = src[k];                                                        \
        t[row][seg * 4 + 0] = f[0];                                            \
        t[row][seg * 4 + 1] = f[1];                                            \
        t[row][seg * 4 + 2] = f[2];                                            \
        t[row][seg * 4 + 3] = f[3];                                            \
        v2u p = {pack2(f[0], f[1]), pack2(f[2], f[3])};                        \
        *(v2u*)(of_ + (size_t)(r0_ + row) * GN + c0_ + seg * 4) = p;           \
      }                                                                        \
      __syncthreads();                                                         \
      {                                                                        \
        int c = tid >> 2;                                                      \
        int rs = (tid & 3) * 16;                                               \
        v4u p0, p1;                                                            \
        _Pragma("unroll") for (int j = 0; j < 4; ++j) {                        \
          p0[j] = pack2(t[rs + 2 * j][c], t[rs + 2 * j + 1][c]);               \
          p1[j] = pack2(t[rs + 8 + 2 * j][c], t[rs + 9 + 2 * j][c]);           \
        }                                                                      \
        unsigned short* dst_ = ob_ + (size_t)(c0_ + c) * GN + r0_ + rs;        \
        *(v4u*)dst_ = p0;                                                      \
        *(v4u*)(dst_ + 8) = p1;                                                \
      }                                                                        \
      __syncthreads();                                                         \
    }

    TLOAD(ra, 0);
    TLOAD(rb, 1);     // in flight through tile 0's LDS phase
    TPROCESS(ra, 0);
    TLOAD(ra, 2);     // in flight through tile 1's LDS phase
    TPROCESS(rb, 1);
    TLOAD(rb, 3);
    TPROCESS(ra, 2);
    TPROCESS(rb, 3);
#undef TLOAD
#undef TPROCESS
  }
}

// ---------------- Stage 4/5: batched bf16 GEMM (round-12 passing version) ---
#define SWZ(r, s) ((s) ^ ((r) & 7))

template <bool OUTF32>
__global__ __launch_bounds__(256) void gemm_bt(const unsigned short* __restrict__ A,
                                               const unsigned short* __restrict__ Bt,
                                               void* __restrict__ Cv) {
  __shared__ unsigned short At[2][128 * 64];  // 2 x 16 KiB
  __shared__ unsigned short Bs[2][128 * 64];
  int bid = blockIdx.x;
  int swz = (bid & 7) * 64 + (bid >> 3);  // XCD-chunked, bijective
  int b = swz >> 4;
  int row0 = ((swz >> 2) & 3) * 128;
  int col0 = (swz & 3) * 128;
  int tid = threadIdx.x, lane = tid & 63, wave = tid >> 6;
  int wr = wave >> 1, wc = wave & 1;
  const unsigned short* Ab = A + (size_t)b * GN * GN;
  const unsigned short* Bb = Bt + (size_t)b * GN * GN;

  v4f acc[4][4];
#pragma unroll
  for (int i = 0; i < 4; ++i)
#pragma unroll
    for (int j = 0; j < 4; ++j) acc[i][j] = (v4f){0.f, 0.f, 0.f, 0.f};

  int cc_r[4], cc_s[4];
#pragma unroll
  for (int i = 0; i < 4; ++i) {
    int c = i * 256 + tid;
    cc_r[i] = c >> 3;
    cc_s[i] = SWZ(c >> 3, c & 7);
  }

#define STAGE(buf, kt)                                                                   \
  {                                                                                      \
    _Pragma("unroll") for (int i = 0; i < 4; ++i) {                                      \
      const unsigned short* ga = Ab + (size_t)(row0 + cc_r[i]) * GN + (kt)*64 + cc_s[i] * 8; \
      const unsigned short* gb = Bb + (size_t)(col0 + cc_r[i]) * GN + (kt)*64 + cc_s[i] * 8; \
      GLOAD16(ga, (char*)&At[buf][0] + (i * 256 + wave * 64) * 16);                      \
      GLOAD16(gb, (char*)&Bs[buf][0] + (i * 256 + wave * 64) * 16);                      \
    }                                                                                    \
  }

#define COMPUTE(buf)                                                                     \
  {                                                                                      \
    int lr = lane & 15, s16 = lane >> 4;                                                 \
    _Pragma("unroll") for (int h = 0; h < 2; ++h) {                                      \
      int sl = h * 4 + s16;                                                              \
      v8bf af[4], bfv[4];                                                                \
      _Pragma("unroll") for (int i = 0; i < 4; ++i) {                                    \
        int r = wr * 64 + i * 16 + lr;                                                   \
        af[i] = *(const v8bf*)&At[buf][r * 64 + SWZ(r, sl) * 8];                         \
      }                                                                                  \
      _Pragma("unroll") for (int j = 0; j < 4; ++j) {                                    \
        int r = wc * 64 + j * 16 + lr;                                                   \
        bfv[j] = *(const v8bf*)&Bs[buf][r * 64 + SWZ(r, sl) * 8];                        \
      }                                                                                  \
      _Pragma("unroll") for (int i = 0; i < 4; ++i)                                      \
          _Pragma("unroll") for (int j = 0; j < 4; ++j) acc[i][j] =                      \
          __builtin_amdgcn_mfma_f32_16x16x32_bf16(af[i], bfv[j], acc[i][j], 0, 0, 0);    \
    }                                                                                    \
  }

  STAGE(0, 0);
  VMCNT0;
  __builtin_amdgcn_s_barrier();
#pragma unroll
  for (int kt = 0; kt < 7; ++kt) {
    int cur = kt & 1;
    STAGE(cur ^ 1, kt + 1);
    COMPUTE(cur);
    VMCNT0;
    __builtin_amdgcn_s_barrier();
  }
  COMPUTE(1);

  int lc = lane & 15;
  int lrow4 = (lane >> 4) * 4;
#pragma unroll
  for (int i = 0; i < 4; ++i) {
#pragma unroll
    for (int j = 0; j < 4; ++j) {
      int gr = row0 + wr * 64 + i * 16 + lrow4;
      int gc = col0 + wc * 64 + j * 16 + lc;
#pragma unroll
      for (int e = 0; e < 4; ++e) {
        float v = acc[i][j][e];
        if constexpr (OUTF32)
          ((float*)Cv)[(size_t)b * GN * GN + (size_t)(gr + e) * GN + gc] = v;
        else
          ((unsigned short*)Cv)[(size_t)b * GN * GN + (size_t)(gr + e) * GN + gc] =
              (unsigned short)f2bf(v);
      }
    }
  }
#undef STAGE
#undef COMPUTE
}

// ---------------- launch ----------------------------------------------------
extern "C" void kernel_launch(void* const* d_in, const int* in_sizes, int n_in,
                              void* d_out, int out_size, void* d_ws, size_t ws_size,
                              hipStream_t stream) {
  const float* receiver  = (const float*)d_in[0];
  const float* attendant = (const float*)d_in[1];
  const float* adj       = (const float*)d_in[2];
  const float* wq        = (const float*)d_in[3];
  const float* wk        = (const float*)d_in[4];
  const float* bias      = (const float*)d_in[5];
  const float* avec      = (const float*)d_in[6];
  float* out = (float*)d_out;

  char* ws = (char*)d_ws;
  float* ekbuf          = (float*)(ws);                          // 2 MiB
  float* eqbuf          = (float*)(ws + (2u << 20));             // 2 MiB
  unsigned short* Et    = (unsigned short*)(ws + (4u << 20));    // 16 MiB
  unsigned short* adjT  = (unsigned short*)(ws + (20u << 20));   // 16 MiB
  unsigned short* adjBF = (unsigned short*)(ws + (36u << 20));   // 16 MiB
  unsigned short* Tbuf  = (unsigned short*)(ws + (52u << 20));   // 16 MiB

  kq_kernel<<<dim3(2048), dim3(256), 0, stream>>>(receiver, attendant, wq, wk, bias,
                                                  ekbuf, eqbuf);
  prep2_kernel<<<dim3(2560), dim3(256), 0, stream>>>(adj, ekbuf, eqbuf, avec,
                                                     adjT, adjBF, Et);
  // T = adjBF @ Et^T  -> bf16
  gemm_bt<false><<<dim3(512), dim3(256), 0, stream>>>(adjBF, Et, Tbuf);
  // out = Tbuf @ adjT^T -> f32
  gemm_bt<true><<<dim3(512), dim3(256), 0, stream>>>(Tbuf, adjT, out);
}